// Round 3
// baseline (32.567 us; speedup 1.0000x reference)
//
#include <hip/hip_runtime.h>
#include <hip/hip_bf16.h>

#define BATCH 4
#define IC 64
#define OC 128
#define HSZ 56
#define WSZ 56
#define HW 3136            // 56*56
#define KTOT 576           // 9 taps * 64 in_ch
#define GUARD 64           // zero guard pixels at each end of xbf
#define XPIX (HW + 2*GUARD)   // 3264 rows per image in xbf

typedef __attribute__((ext_vector_type(8))) short bf16x8;
typedef __attribute__((ext_vector_type(4))) float f32x4;

// ---------------- prep: x transpose->bf16 (with zero guards) + W convert ----
// blocks 0..815:    xcvt  (b = blk/204, 64-px tile = blk%204, covers pix -64..3199)
// blocks 816..1103: wcvt  (Wb[o][k] bf16, k = tap*64 + ch)
__global__ __launch_bounds__(256) void prep_kernel(
    const float* __restrict__ x,            // [B][64][3136] f32
    const float* __restrict__ W,            // [128][64][3][3] f32
    unsigned short* __restrict__ Wb,        // [128][576] bf16
    unsigned short* __restrict__ xbf)       // [B][3264][64] bf16
{
    const int blk = blockIdx.x;
    const int t   = threadIdx.x;

    if (blk < BATCH * 51) {                 // 51 tiles of 64 px cover 3264 rows
        const int b    = blk / 51;
        const int tile = blk - b * 51;
        const int px   = (t & 63);
        const int chg  = t >> 6;            // 0..3 -> 16 channels each
        const int gp   = tile * 64 - GUARD + px;   // [-64, 3200)
        const bool inb = (unsigned)gp < (unsigned)HW;
        const float* xb = x + (size_t)b * IC * HW;

        unsigned short __attribute__((aligned(16))) v[16];
#pragma unroll
        for (int i = 0; i < 16; ++i) {
            const int ch = chg * 16 + i;
            float f = inb ? xb[ch * HW + gp] : 0.0f;
            __hip_bfloat16 h = __float2bfloat16(f);
            v[i] = *reinterpret_cast<unsigned short*>(&h);
        }
        unsigned short* dst = xbf + ((size_t)b * XPIX + (gp + GUARD)) * IC + chg * 16;
        *reinterpret_cast<uint4*>(dst)     = *reinterpret_cast<uint4*>(&v[0]);
        *reinterpret_cast<uint4*>(dst + 8) = *reinterpret_cast<uint4*>(&v[8]);
    } else {
        const int j = (blk - BATCH * 51) * 256 + t;   // 0..73727
        if (j < OC * KTOT) {
            const int o   = j / KTOT;
            const int k   = j - o * KTOT;
            const int tap = k >> 6;
            const int ch  = k & 63;
            __hip_bfloat16 h = __float2bfloat16(W[(o * IC + ch) * 9 + tap]);
            Wb[j] = *reinterpret_cast<unsigned short*>(&h);
        }
    }
}

// ---------------- conv: implicit GEMM, no LDS, direct L2-resident loads -----
// grid (49, 2, 4): 64-px tile, out-ch half (64), batch. 256 thr = 4 waves (pg).
// Wave: 16 pixels x 64 out_ch, K = 576. 72 MFMA / wave.
__global__ __launch_bounds__(256) void conv_mfma_kernel(
    const unsigned short* __restrict__ xbf, // [B][3264][64] bf16
    const unsigned short* __restrict__ Wb,  // [128][576] bf16
    const float* __restrict__ bias,         // [128] f32
    float* __restrict__ out)                // [B][128][3136] f32
{
    const int t    = threadIdx.x;
    const int lane = t & 63;
    const int pg   = t >> 6;                // wave id 0..3
    const int lrow = lane & 15;             // A-row (pixel) / B-col (out_ch)
    const int lk   = lane >> 4;             // k-chunk 0..3

    const int p0 = blockIdx.x * 64;
    const int og = blockIdx.y;              // 0..1
    const int b  = blockIdx.z;

    const int apix = p0 + pg * 16 + lrow;
    const int ah = apix / WSZ;
    const int aw = apix - ah * WSZ;

    // per-(pixel,tap) validity (horizontal wrap + vertical edges)
    unsigned vmask = 0;
#pragma unroll
    for (int tp = 0; tp < 9; ++tp) {
        const int hh = ah + (tp / 3) - 1;
        const int ww = aw + (tp % 3) - 1;
        if ((unsigned)hh < (unsigned)HSZ && (unsigned)ww < (unsigned)WSZ)
            vmask |= (1u << tp);
    }

    // A base: this lane's pixel row in xbf (guard-shifted), element units
    const unsigned short* xa = xbf + ((size_t)b * XPIX + GUARD + apix) * IC + lk * 8;
    // B base: Wb[o][k], o = og*64 + bg*16 + lrow
    const unsigned short* wb = Wb + (size_t)(og * 64 + lrow) * KTOT + lk * 8;

    f32x4 acc[4] = {{0,0,0,0},{0,0,0,0},{0,0,0,0},{0,0,0,0}};
    const bf16x8 zfrag = {0,0,0,0,0,0,0,0};

#pragma unroll
    for (int tp = 0; tp < 9; ++tp) {
        const int toff = ((tp / 3) - 1) * WSZ + ((tp % 3) - 1);   // flat tap offset
        const bool valid = (vmask >> tp) & 1u;
        const unsigned short* xrow = xa + toff * IC;
#pragma unroll
        for (int half = 0; half < 2; ++half) {
            bf16x8 a = *reinterpret_cast<const bf16x8*>(xrow + half * 32);
            a = valid ? a : zfrag;
            const unsigned short* wp = wb + tp * 64 + half * 32;
            bf16x8 b0 = *reinterpret_cast<const bf16x8*>(wp);
            bf16x8 b1 = *reinterpret_cast<const bf16x8*>(wp + 16 * KTOT);
            bf16x8 b2 = *reinterpret_cast<const bf16x8*>(wp + 32 * KTOT);
            bf16x8 b3 = *reinterpret_cast<const bf16x8*>(wp + 48 * KTOT);
            acc[0] = __builtin_amdgcn_mfma_f32_16x16x32_bf16(a, b0, acc[0], 0, 0, 0);
            acc[1] = __builtin_amdgcn_mfma_f32_16x16x32_bf16(a, b1, acc[1], 0, 0, 0);
            acc[2] = __builtin_amdgcn_mfma_f32_16x16x32_bf16(a, b2, acc[2], 0, 0, 0);
            acc[3] = __builtin_amdgcn_mfma_f32_16x16x32_bf16(a, b3, acc[3], 0, 0, 0);
        }
    }

    // D: row = 4*lk + reg (pixel), col = lrow (out_ch) -> f32x4 store, full lines
    const int pstore = p0 + pg * 16 + 4 * lk;
#pragma unroll
    for (int bg = 0; bg < 4; ++bg) {
        const int o = og * 64 + bg * 16 + lrow;
        f32x4 r = acc[bg] + bias[o];
        *reinterpret_cast<f32x4*>(&out[((size_t)(b * OC + o)) * HW + pstore]) = r;
    }
}

extern "C" void kernel_launch(void* const* d_in, const int* in_sizes, int n_in,
                              void* d_out, int out_size, void* d_ws, size_t ws_size,
                              hipStream_t stream) {
    const float* x    = (const float*)d_in[0];
    const float* W    = (const float*)d_in[1];
    const float* bias = (const float*)d_in[2];
    float* out        = (float*)d_out;

    unsigned short* Wb  = (unsigned short*)d_ws;                    // 147456 B
    unsigned short* xbf = (unsigned short*)((char*)d_ws + 147456);  // 4*3264*64*2 B

    const int wblocks = (OC * KTOT + 255) / 256;       // 288
    prep_kernel<<<BATCH * 51 + wblocks, 256, 0, stream>>>(x, W, Wb, xbf);

    dim3 grid(HW / 64, 2, BATCH);                      // (49, 2, 4)
    conv_mfma_kernel<<<grid, 256, 0, stream>>>(xbf, Wb, bias, out);
}